// Round 3
// baseline (1261.649 us; speedup 1.0000x reference)
//
#include <hip/hip_runtime.h>
#include <hip/hip_bf16.h>
#include <float.h>
#include <math.h>

typedef __hip_bfloat16 bf16;

__device__ __forceinline__ float bf2f(bf16 v){ return __bfloat162float(v); }
__device__ __forceinline__ void stv(float* p, float v){ *p = v; }
__device__ __forceinline__ void stv(bf16* p, float v){ *p = __float2bfloat16(v); }
__device__ __forceinline__ float nanfix(float v){
  if (v != v) return 0.f;
  return fminf(fmaxf(v, -FLT_MAX), FLT_MAX);
}

// ---------------- sorting / misc ----------------
__global__ void k_deg(const int* __restrict__ tgt, int* __restrict__ deg, int E){
  int e = blockIdx.x*blockDim.x + threadIdx.x;
  if (e < E) atomicAdd(&deg[tgt[e]], 1);
}

__global__ void k_scan(const int* __restrict__ deg, int* __restrict__ offs, int N){
  __shared__ int sm[1024];
  __shared__ int carry_s;
  int tid = threadIdx.x;
  if (tid == 0){ offs[0] = 0; carry_s = 0; }
  __syncthreads();
  for (int base = 0; base < N; base += 1024){
    int i = base + tid;
    int v = (i < N) ? deg[i] : 0;
    sm[tid] = v; __syncthreads();
    for (int off = 1; off < 1024; off <<= 1){
      int t = (tid >= off) ? sm[tid-off] : 0;
      __syncthreads();
      sm[tid] += t;
      __syncthreads();
    }
    int carry = carry_s;
    if (i < N) offs[i+1] = carry + sm[tid];
    __syncthreads();
    if (tid == 0) carry_s += sm[1023];
    __syncthreads();
  }
}

__global__ void k_scatter(const int* __restrict__ src, const int* __restrict__ tgt,
                          const int* __restrict__ offs, int* __restrict__ cnt,
                          int* __restrict__ ssrc, int E){
  int e = blockIdx.x*blockDim.x + threadIdx.x;
  if (e < E){
    int t = tgt[e];
    int pos = offs[t] + atomicAdd(&cnt[t], 1);
    ssrc[pos] = src[e];
  }
}

// ---------------- weight repacks (float32 inputs) ----------------
// Wpq[c, t*F+f] = preW[t,c,f]; Wpq[c, NC + t*F+f] = preW[t,K+c,f]; bias first half only
__global__ void k_repack_pq(const float* __restrict__ preW, const float* __restrict__ preB,
                            float* __restrict__ Wpq, float* __restrict__ bpq,
                            int K, int F, int T){
  int NC = T*F;
  int total = K*2*NC;
  int idx = blockIdx.x*blockDim.x + threadIdx.x;
  if (idx < total){
    int c = idx/(2*NC); int col = idx%(2*NC);
    int half = col/NC; int j = col%NC; int t = j/F; int f = j%F;
    Wpq[idx] = preW[(t*2*K + half*K + c)*F + f];
  }
  if (idx < 2*NC) bpq[idx] = (idx < NC) ? preB[idx] : 0.f;
}

// Wx[c*NC+j] = postW[t,c,f] ; Wagg4[((t*4F+cc)*F+f)*4 + s] = postW[t, KX + s*4F + cc, f] (s<3, pad s=3 -> 0)
__global__ void k_repack_post4(const float* __restrict__ postW, const float* __restrict__ postB,
                               float* __restrict__ Wx, float* __restrict__ Wagg4,
                               float* __restrict__ bpost, int KX, int F, int T){
  int NC = T*F; int KP = KX + 12*F;
  int totalx = KX*NC; int totala = T*4*F*F*4;
  int idx = blockIdx.x*blockDim.x + threadIdx.x;
  if (idx < totalx){
    int c = idx/NC; int j = idx%NC; int t = j/F; int f = j%F;
    Wx[idx] = postW[(t*KP + c)*F + f];
  } else if (idx < totalx + totala){
    int i2 = idx - totalx;
    int s = i2 % 4; int r = i2 / 4;
    int f = r % F; r /= F;
    int cc = r % (4*F); int t = r / (4*F);
    Wagg4[i2] = (s < 3) ? postW[(t*KP + KX + s*4*F + cc)*F + f] : 0.f;
  }
  if (idx < NC) bpost[idx] = postB[idx];
}

// ---------------- generic 64x64 tiled GEMM: out[N,NC] = A[N,K] @ W[K,NC] + bias ----------------
template<typename TO>
__global__ __launch_bounds__(256) void k_gemm(const float* __restrict__ A, int N, int K,
                       const float* __restrict__ W, int NC,
                       const float* __restrict__ bias, TO* __restrict__ out){
  __shared__ float As[16][68];
  __shared__ float Ws[16][64];
  int tid = threadIdx.x;
  int n0 = blockIdx.x*64, j0 = blockIdx.y*64;
  int ty = tid/16, tx = tid%16;
  int a_n = tid/4, a_k = (tid%4)*4;
  int w_k = tid/16, w_j = (tid%16)*4;
  float acc[4][4] = {};
  for (int k0 = 0; k0 < K; k0 += 16){
    int n = n0 + a_n;
    float4 av = make_float4(0.f,0.f,0.f,0.f);
    if (n < N) av = *(const float4*)(A + (size_t)n*K + k0 + a_k);
    As[a_k+0][a_n]=av.x; As[a_k+1][a_n]=av.y; As[a_k+2][a_n]=av.z; As[a_k+3][a_n]=av.w;
    float4 wv = *(const float4*)(W + (size_t)(k0+w_k)*NC + j0 + w_j);
    *(float4*)&Ws[w_k][w_j] = wv;
    __syncthreads();
    #pragma unroll
    for (int kk = 0; kk < 16; kk++){
      float a[4], b[4];
      #pragma unroll
      for (int i=0;i<4;i++) a[i] = As[kk][ty*4+i];
      #pragma unroll
      for (int jj=0;jj<4;jj++) b[jj] = Ws[kk][tx*4+jj];
      #pragma unroll
      for (int i=0;i<4;i++)
        #pragma unroll
        for (int jj=0;jj<4;jj++) acc[i][jj] += a[i]*b[jj];
    }
    __syncthreads();
  }
  #pragma unroll
  for (int i=0;i<4;i++){
    int n = n0 + ty*4 + i;
    if (n < N){
      #pragma unroll
      for (int jj=0;jj<4;jj++){
        int col = j0 + tx*4 + jj;
        stv(&out[(size_t)n*NC + col], acc[i][jj] + bias[col]);
      }
    }
  }
}

// ---------------- per-node PNA aggregation ----------------
// PQ: [N, 2*NC] bf16 (P = tgt-half incl bias, Q = src-half). agg out: [N, T*4F] fp32.
template<int NC, int F>
__global__ void k_agg(const bf16* __restrict__ PQ,
                      const int* __restrict__ ssrc, const int* __restrict__ offs,
                      const float* __restrict__ avgp,
                      float* __restrict__ agg, float* __restrict__ scal, int N){
  int n = blockIdx.x; if (n >= N) return;
  int tid = threadIdx.x;
  float p = bf2f(PQ[(size_t)n*2*NC + tid]);
  int s0 = offs[n], s1 = offs[n+1];
  float sum = 0.f, sq = 0.f, mn = FLT_MAX, mx = -FLT_MAX;
  for (int i = s0; i < s1; i++){
    int s = ssrc[i];
    float m = p + bf2f(PQ[(size_t)s*2*NC + NC + tid]);
    sum += m; sq += m*m; mn = fminf(mn, m); mx = fmaxf(mx, m);
  }
  int deg = s1 - s0;
  float degc = fmaxf((float)deg, 1.f);
  float mean = sum/degc;
  float var = fmaxf(sq/degc - mean*mean, 0.f);
  float sd = sqrtf(var + 1e-5f);
  if (deg == 0){ mn = 0.f; mx = 0.f; }
  int t = tid / F, ff = tid % F;
  size_t base = (size_t)n*4*NC + t*4*F;
  agg[base + ff]       = mean;
  agg[base + F  + ff]  = mn;
  agg[base + 2*F + ff] = mx;
  agg[base + 3*F + ff] = sd;
  if (tid == 0){
    float dlog = logf(degc + 1.f);
    float avg = *avgp;
    scal[2*n]   = dlog/avg;
    scal[2*n+1] = avg/dlog;
  }
}

// ---------------- post-tower GEMM with PNA scalers (block-diagonal over towers) ----------------
// grid (ceil(N/TN), T); block 256 = (F/2 col-pair lanes) x SUBS node-subsets
// A-tiles in LDS (k-fast, stride TN+2), weights streamed: Wx float2, Wagg4 2x float4.
template<int F, int KX, int TN>
__global__ __launch_bounds__(256) void k_post(const float* __restrict__ X,
      const float* __restrict__ agg,
      const float* __restrict__ Wx, const float* __restrict__ Wagg4,
      const float* __restrict__ bias, const float* __restrict__ scal,
      float* __restrict__ out, int N, int T){
  const int K4F = 4*F;
  const int LD = TN + 2;        // 8B-aligned rows, low-conflict staging
  const int HF = F/2;           // col-pairs per tower
  const int SUBS = 256/HF;
  const int MY = TN/SUBS;
  __shared__ float lx[KX*LD];
  __shared__ float la[K4F*LD];
  int t0 = blockIdx.y; int NC = T*F;
  int n0 = blockIdx.x*TN;
  int tid = threadIdx.x;
  for (int idx = tid; idx < KX*TN; idx += 256){
    int c = idx % KX, k = idx / KX; int n = n0 + k;
    lx[c*LD + k] = (n < N) ? X[(size_t)n*KX + c] : 0.f;
  }
  for (int idx = tid; idx < K4F*TN; idx += 256){
    int cc = idx % K4F, k = idx / K4F; int n = n0 + k;
    la[cc*LD + k] = (n < N) ? agg[(size_t)n*(4*NC) + t0*K4F + cc] : 0.f;
  }
  __syncthreads();
  int fp = tid % HF, sub = tid / HF;
  int kbase = sub*MY;
  int j = t0*F + 2*fp;
  float acc0[MY][2] = {}, acc1[MY][2] = {}, acc2[MY][2] = {};
  for (int c = 0; c < KX; c++){
    float2 w = *(const float2*)(Wx + (size_t)c*NC + j);
    const float* ap = &lx[c*LD + kbase];
    #pragma unroll
    for (int m = 0; m < MY; m++){
      float a = ap[m];
      acc0[m][0] += a*w.x; acc0[m][1] += a*w.y;
    }
  }
  for (int cc = 0; cc < K4F; cc++){
    const float* wp = Wagg4 + ((size_t)(t0*K4F + cc)*F + 2*fp)*4;
    float4 w0 = *(const float4*)wp;        // col j  : s0,s1,s2,pad
    float4 w1 = *(const float4*)(wp + 4);  // col j+1
    const float* ap = &la[cc*LD + kbase];
    #pragma unroll
    for (int m = 0; m < MY; m++){
      float a = ap[m];
      acc0[m][0] += a*w0.x; acc1[m][0] += a*w0.y; acc2[m][0] += a*w0.z;
      acc0[m][1] += a*w1.x; acc1[m][1] += a*w1.y; acc2[m][1] += a*w1.z;
    }
  }
  float bj0 = bias[j], bj1 = bias[j+1];
  #pragma unroll
  for (int m = 0; m < MY; m++){
    int n = n0 + kbase + m;
    if (n < N){
      float s1v = scal[2*n], s2v = scal[2*n+1];
      out[(size_t)n*NC + j]   = bj0 + acc0[m][0] + s1v*acc1[m][0] + s2v*acc2[m][0];
      out[(size_t)n*NC + j+1] = bj1 + acc0[m][1] + s1v*acc1[m][1] + s2v*acc2[m][1];
    }
  }
}

// ---------------- batch norm ----------------
template<int C>
__global__ void k_bn_stats(const float* __restrict__ h, float* __restrict__ stats, int N){
  int c = threadIdx.x;
  int n0 = blockIdx.x*256;
  int n1 = min(n0 + 256, N);
  float s = 0.f, q = 0.f;
  for (int n = n0; n < n1; n++){
    float v = nanfix(h[(size_t)n*C + c]);
    s += v; q += v*v;
  }
  atomicAdd(&stats[c], s);
  atomicAdd(&stats[C + c], q);
}

template<typename TO, int C>
__global__ void k_bn_apply(const float* __restrict__ h, const float* __restrict__ stats,
     const float* __restrict__ g, const float* __restrict__ b,
     TO* __restrict__ out, int N){
  int idx = blockIdx.x*blockDim.x + threadIdx.x;
  if (idx >= N*C) return;
  int c = idx % C;
  float fn = (float)N;
  float m = stats[c]/fn;
  float var = fmaxf(stats[C + c]/fn - m*m, 0.f);
  float inv = rsqrtf(var + 1e-5f);
  float v = nanfix(h[idx]);
  float r = g[c]*(v - m)*inv + b[c];
  stv(&out[idx], fmaxf(r, 0.f));
}

static inline int cdiv(int a, int b){ return (a + b - 1)/b; }

extern "C" void kernel_launch(void* const* d_in, const int* in_sizes, int n_in,
                              void* d_out, int out_size, void* d_ws, size_t ws_size,
                              hipStream_t stream){
  const int IN = 128, HID = 256, T = 4, F1 = 64, F2 = 32;
  const int N = in_sizes[0]/IN;
  const int E = in_sizes[1]/2;

  const float* x      = (const float*)d_in[0];
  const int*   ei     = (const int*)  d_in[1];
  const int*   srcE   = ei;
  const int*   tgtE   = ei + E;
  const float* avgp   = (const float*)d_in[2];
  const float* pre1W  = (const float*)d_in[3];
  const float* pre1b  = (const float*)d_in[4];
  const float* post1W = (const float*)d_in[5];
  const float* post1b = (const float*)d_in[6];
  const float* lin1W  = (const float*)d_in[7];   // [T*F1, HID] row-major: use directly
  const float* lin1b  = (const float*)d_in[8];
  const float* bn1g   = (const float*)d_in[9];
  const float* bn1b   = (const float*)d_in[10];
  const float* pre2W  = (const float*)d_in[11];
  const float* pre2b  = (const float*)d_in[12];
  const float* post2W = (const float*)d_in[13];
  const float* post2b = (const float*)d_in[14];
  const float* lin2W  = (const float*)d_in[15];  // [T*F2, 128] row-major: use directly
  const float* lin2b  = (const float*)d_in[16];
  const float* bn2g   = (const float*)d_in[17];
  const float* bn2b   = (const float*)d_in[18];

  // ---- workspace carve ----
  char* w = (char*)d_ws;
  auto alloc = [&](size_t bytes)->void*{
    void* p = (void*)w; w += (bytes + 255) & ~(size_t)255; return p;
  };
  float* Wpq1   = (float*)alloc((size_t)IN*2*T*F1*4);   float* bpq1 = (float*)alloc(2*T*F1*4);
  float* Wx1    = (float*)alloc((size_t)IN*T*F1*4);
  float* Wagg1  = (float*)alloc((size_t)T*4*F1*F1*4*4); float* bpost1 = (float*)alloc(T*F1*4);
  float* Wpq2   = (float*)alloc((size_t)HID*2*T*F2*4);  float* bpq2 = (float*)alloc(2*T*F2*4);
  float* Wx2    = (float*)alloc((size_t)HID*T*F2*4);
  float* Wagg2  = (float*)alloc((size_t)T*4*F2*F2*4*4); float* bpost2 = (float*)alloc(T*F2*4);
  int* deg_i    = (int*)alloc((size_t)N*4);
  int* offs     = (int*)alloc((size_t)(N+1)*4);
  int* cnt      = (int*)alloc((size_t)N*4);
  int* ssrc     = (int*)alloc((size_t)E*4);
  bf16* PQ      = (bf16*)alloc((size_t)N*512*2);
  float* aggb   = (float*)alloc((size_t)N*1024*4);
  float* scal   = (float*)alloc((size_t)N*2*4);
  float* postb  = (float*)alloc((size_t)N*256*4);
  float* hpre   = (float*)alloc((size_t)N*256*4);
  float* h1     = (float*)alloc((size_t)N*256*4);
  float* stats  = (float*)alloc(1024*4);   // [0..511] layer1, [512..1023] layer2

  // ---- zero accumulators ----
  hipMemsetAsync(deg_i, 0, (size_t)N*4, stream);
  hipMemsetAsync(cnt,   0, (size_t)N*4, stream);
  hipMemsetAsync(stats, 0, 1024*4, stream);

  // ---- repack weights ----
  k_repack_pq<<<cdiv(IN*2*T*F1,256),256,0,stream>>>(pre1W, pre1b, Wpq1, bpq1, IN, F1, T);
  k_repack_post4<<<cdiv(IN*T*F1 + T*4*F1*F1*4,256),256,0,stream>>>(post1W, post1b, Wx1, Wagg1, bpost1, IN, F1, T);
  k_repack_pq<<<cdiv(HID*2*T*F2,256),256,0,stream>>>(pre2W, pre2b, Wpq2, bpq2, HID, F2, T);
  k_repack_post4<<<cdiv(HID*T*F2 + T*4*F2*F2*4,256),256,0,stream>>>(post2W, post2b, Wx2, Wagg2, bpost2, HID, F2, T);

  // ---- counting sort of edges by target ----
  k_deg<<<cdiv(E,256),256,0,stream>>>(tgtE, deg_i, E);
  k_scan<<<1,1024,0,stream>>>(deg_i, offs, N);
  k_scatter<<<cdiv(E,256),256,0,stream>>>(srcE, tgtE, offs, cnt, ssrc, E);

  // ================= Layer 1 =================
  { dim3 g(cdiv(N,64), (2*T*F1)/64);
    k_gemm<bf16><<<g,256,0,stream>>>(x, N, IN, Wpq1, 2*T*F1, bpq1, PQ); }
  k_agg<256,64><<<N,256,0,stream>>>(PQ, ssrc, offs, avgp, aggb, scal, N);
  { dim3 g(cdiv(N,32), T);
    k_post<64,128,32><<<g,256,0,stream>>>(x, aggb, Wx1, Wagg1, bpost1, scal, postb, N, T); }
  { dim3 g(cdiv(N,64), HID/64);
    k_gemm<float><<<g,256,0,stream>>>(postb, N, T*F1, lin1W, HID, lin1b, hpre); }
  k_bn_stats<256><<<cdiv(N,256),256,0,stream>>>(hpre, stats, N);
  k_bn_apply<float,256><<<cdiv(N*256,256),256,0,stream>>>(hpre, stats, bn1g, bn1b, h1, N);

  // ================= Layer 2 =================
  { dim3 g(cdiv(N,64), (2*T*F2)/64);
    k_gemm<bf16><<<g,256,0,stream>>>(h1, N, HID, Wpq2, 2*T*F2, bpq2, PQ); }
  k_agg<128,32><<<N,128,0,stream>>>(PQ, ssrc, offs, avgp, aggb, scal, N);
  { dim3 g(cdiv(N,32), T);
    k_post<32,256,32><<<g,256,0,stream>>>(h1, aggb, Wx2, Wagg2, bpost2, scal, postb, N, T); }
  { dim3 g(cdiv(N,64), 128/64);
    k_gemm<float><<<g,256,0,stream>>>(postb, N, T*F2, lin2W, 128, lin2b, hpre); }
  k_bn_stats<128><<<cdiv(N,256),128,0,stream>>>(hpre, stats + 512, N);
  k_bn_apply<float,128><<<cdiv(N*128,256),256,0,stream>>>(hpre, stats + 512, bn2g, bn2b, (float*)d_out, N);
}

// Round 4
// 678.962 us; speedup vs baseline: 1.8582x; 1.8582x over previous
//
#include <hip/hip_runtime.h>
#include <hip/hip_bf16.h>
#include <float.h>
#include <math.h>

typedef __hip_bfloat16 bf16;
typedef __attribute__((ext_vector_type(8))) short short8;
typedef __attribute__((ext_vector_type(4))) float f32x4;

__device__ __forceinline__ float bf2f(bf16 v){ return __bfloat162float(v); }
__device__ __forceinline__ void stv(float* p, float v){ *p = v; }
__device__ __forceinline__ void stv(bf16* p, float v){ *p = __float2bfloat16(v); }
__device__ __forceinline__ float nanfix(float v){
  if (v != v) return 0.f;
  return fminf(fmaxf(v, -FLT_MAX), FLT_MAX);
}

// ---------------- sorting / misc ----------------
__global__ void k_deg(const int* __restrict__ tgt, int* __restrict__ deg, int E){
  int e = blockIdx.x*blockDim.x + threadIdx.x;
  if (e < E) atomicAdd(&deg[tgt[e]], 1);
}

__global__ void k_scan(const int* __restrict__ deg, int* __restrict__ offs, int N){
  __shared__ int sm[1024];
  __shared__ int carry_s;
  int tid = threadIdx.x;
  if (tid == 0){ offs[0] = 0; carry_s = 0; }
  __syncthreads();
  for (int base = 0; base < N; base += 1024){
    int i = base + tid;
    int v = (i < N) ? deg[i] : 0;
    sm[tid] = v; __syncthreads();
    for (int off = 1; off < 1024; off <<= 1){
      int t = (tid >= off) ? sm[tid-off] : 0;
      __syncthreads();
      sm[tid] += t;
      __syncthreads();
    }
    int carry = carry_s;
    if (i < N) offs[i+1] = carry + sm[tid];
    __syncthreads();
    if (tid == 0) carry_s += sm[1023];
    __syncthreads();
  }
}

__global__ void k_scatter(const int* __restrict__ src, const int* __restrict__ tgt,
                          const int* __restrict__ offs, int* __restrict__ cnt,
                          int* __restrict__ ssrc, int E){
  int e = blockIdx.x*blockDim.x + threadIdx.x;
  if (e < E){
    int t = tgt[e];
    int pos = offs[t] + atomicAdd(&cnt[t], 1);
    ssrc[pos] = src[e];
  }
}

__global__ void k_f2b(const float* __restrict__ in, bf16* __restrict__ out, int n){
  int i = blockIdx.x*blockDim.x + threadIdx.x;
  if (i < n) out[i] = __float2bfloat16(in[i]);
}

// ---------------- weight repacks: all produce bf16 B^T [NC][K] ----------------
// WpqT[j][c], j = half*NC + t*F + f  <- preW[t, half*K + c, f]; bpq fp32
__global__ void k_repack_pqT(const float* __restrict__ preW, const float* __restrict__ preB,
                             bf16* __restrict__ WpqT, float* __restrict__ bpq,
                             int K, int F, int T){
  int NC = T*F;
  int total = 2*NC*K;
  int idx = blockIdx.x*blockDim.x + threadIdx.x;
  if (idx < total){
    int j = idx/K, c = idx%K;
    int half = j/NC, jj = j%NC, t = jj/F, f = jj%F;
    WpqT[idx] = __float2bfloat16(preW[(t*2*K + half*K + c)*F + f]);
  }
  if (idx < 2*NC) bpq[idx] = (idx < NC) ? preB[idx] : 0.f;
}

// WxT[j][c] <- postW[t*KP + c, f]; WaggT[t*F + f][k] <- postW[t*KP + KX + k, f]; bpost fp32
__global__ void k_repack_postT(const float* __restrict__ postW, const float* __restrict__ postB,
                               bf16* __restrict__ WxT, bf16* __restrict__ WaggT,
                               float* __restrict__ bpost, int KX, int F, int T){
  int NC = T*F; int KP = KX + 12*F;
  int totalx = NC*KX; int totala = NC*12*F;
  int idx = blockIdx.x*blockDim.x + threadIdx.x;
  if (idx < totalx){
    int j = idx/KX, c = idx%KX, t = j/F, f = j%F;
    WxT[idx] = __float2bfloat16(postW[(t*KP + c)*F + f]);
  } else if (idx < totalx + totala){
    int i2 = idx - totalx;
    int row = i2/(12*F), k = i2%(12*F);
    int t = row/F, f = row%F;
    WaggT[i2] = __float2bfloat16(postW[(t*KP + KX + k)*F + f]);
  }
  if (idx < NC) bpost[idx] = postB[idx];
}

// WlinT[j][c] <- linW[c*NC + j]
__global__ void k_repack_linT(const float* __restrict__ linW, bf16* __restrict__ WlinT,
                              int K, int NC){
  int idx = blockIdx.x*blockDim.x + threadIdx.x;
  if (idx < NC*K){
    int j = idx/K, c = idx%K;
    WlinT[idx] = __float2bfloat16(linW[c*NC + j]);
  }
}

// ---------------- MFMA GEMM: C[N, *] = A[N,K](bf16) @ Bt[NC,K]^T (bf16) ----------------
// 64x64 tile, 4 waves, each wave 32x32 via 2x2 mfma_f32_16x16x32_bf16.
// z-dim: A += z*AzStride, Bt += z*BzStride, global col = z*czStride + local col.
template<typename TO>
__global__ __launch_bounds__(256) void k_mgemm(
    const bf16* __restrict__ A, int lda, int AzStride,
    const bf16* __restrict__ Bt, int BzStride,
    const float* __restrict__ bias,
    const float* __restrict__ Cin, TO* __restrict__ Cout, int ldc,
    int N, int K, int NCz, int czStride)
{
  __shared__ __align__(16) bf16 As[64*40];
  __shared__ __align__(16) bf16 Bs[64*40];
  int z = blockIdx.z;
  const bf16* Az = A + (size_t)z*AzStride;
  const bf16* Bz = Bt + (size_t)z*BzStride;
  int n0 = blockIdx.y*64;
  int j0 = blockIdx.x*64;
  int tid = threadIdx.x;
  int srow = tid>>2, skoff = (tid&3)*8;
  int wave = tid>>6, lane = tid&63;
  int wy = (wave>>1)*32, wx = (wave&1)*32;
  int l15 = lane&15, q = lane>>4;
  f32x4 acc[2][2] = {};
  for (int k0 = 0; k0 < K; k0 += 32){
    uint4 av = {0,0,0,0};
    int ar = n0 + srow;
    if (ar < N) av = *(const uint4*)(Az + (size_t)ar*lda + k0 + skoff);
    *(uint4*)&As[srow*40 + skoff] = av;
    uint4 bv = {0,0,0,0};
    int br = j0 + srow;
    if (br < NCz) bv = *(const uint4*)(Bz + (size_t)br*K + k0 + skoff);
    *(uint4*)&Bs[srow*40 + skoff] = bv;
    __syncthreads();
    short8 af[2], bfr[2];
    #pragma unroll
    for (int i = 0; i < 2; i++){
      af[i]  = *(const short8*)&As[(wy + i*16 + l15)*40 + q*8];
      bfr[i] = *(const short8*)&Bs[(wx + i*16 + l15)*40 + q*8];
    }
    #pragma unroll
    for (int mi = 0; mi < 2; mi++)
      #pragma unroll
      for (int ni = 0; ni < 2; ni++)
        acc[mi][ni] = __builtin_amdgcn_mfma_f32_16x16x32_bf16(af[mi], bfr[ni], acc[mi][ni], 0, 0, 0);
    __syncthreads();
  }
  #pragma unroll
  for (int mi = 0; mi < 2; mi++){
    #pragma unroll
    for (int ni = 0; ni < 2; ni++){
      #pragma unroll
      for (int r = 0; r < 4; r++){
        int n  = n0 + wy + mi*16 + q*4 + r;
        int jj = j0 + wx + ni*16 + l15;
        if (n < N && jj < NCz){
          int jg = z*czStride + jj;
          float v = acc[mi][ni][r];
          if (bias) v += bias[jg];
          if (Cin)  v += Cin[(size_t)n*ldc + jg];
          stv(&Cout[(size_t)n*ldc + jg], v);
        }
      }
    }
  }
}

// ---------------- per-node PNA aggregation -> agg12 [N, T*12F] bf16 ----------------
// layout: agg12[n, t*12F + s*4F + kind*F + f], s in {id, amp, att}, kind in {mean,mn,mx,sd}
template<int NC, int F>
__global__ void k_agg12(const bf16* __restrict__ PQ,
                        const int* __restrict__ ssrc, const int* __restrict__ offs,
                        const float* __restrict__ avgp,
                        bf16* __restrict__ agg12, int N){
  int n = blockIdx.x; if (n >= N) return;
  int tid = threadIdx.x;
  float p = bf2f(PQ[(size_t)n*2*NC + tid]);
  int s0 = offs[n], s1 = offs[n+1];
  float sum = 0.f, sq = 0.f, mn = FLT_MAX, mx = -FLT_MAX;
  for (int i = s0; i < s1; i++){
    int s = ssrc[i];
    float m = p + bf2f(PQ[(size_t)s*2*NC + NC + tid]);
    sum += m; sq += m*m; mn = fminf(mn, m); mx = fmaxf(mx, m);
  }
  int deg = s1 - s0;
  float degc = fmaxf((float)deg, 1.f);
  float mean = sum/degc;
  float var = fmaxf(sq/degc - mean*mean, 0.f);
  float sd = sqrtf(var + 1e-5f);
  if (deg == 0){ mn = 0.f; mx = 0.f; }
  float dlog = logf(degc + 1.f);
  float avg = *avgp;
  float sc1 = dlog/avg, sc2 = avg/dlog;
  int t = tid / F, f = tid % F;
  size_t base = (size_t)n*(12*NC) + (size_t)t*(12*F);
  float vals[4] = {mean, mn, mx, sd};
  float scl[3] = {1.f, sc1, sc2};
  #pragma unroll
  for (int s = 0; s < 3; s++){
    #pragma unroll
    for (int k = 0; k < 4; k++){
      agg12[base + s*4*F + k*F + f] = __float2bfloat16(vals[k]*scl[s]);
    }
  }
}

// ---------------- batch norm ----------------
template<int C>
__global__ void k_bn_stats(const float* __restrict__ h, float* __restrict__ stats, int N){
  int c = threadIdx.x;
  int n0 = blockIdx.x*256;
  int n1 = min(n0 + 256, N);
  float s = 0.f, q = 0.f;
  for (int n = n0; n < n1; n++){
    float v = nanfix(h[(size_t)n*C + c]);
    s += v; q += v*v;
  }
  atomicAdd(&stats[c], s);
  atomicAdd(&stats[C + c], q);
}

template<typename TO, int C>
__global__ void k_bn_apply(const float* __restrict__ h, const float* __restrict__ stats,
     const float* __restrict__ g, const float* __restrict__ b,
     TO* __restrict__ out, int N){
  int idx = blockIdx.x*blockDim.x + threadIdx.x;
  if (idx >= N*C) return;
  int c = idx % C;
  float fn = (float)N;
  float m = stats[c]/fn;
  float var = fmaxf(stats[C + c]/fn - m*m, 0.f);
  float inv = rsqrtf(var + 1e-5f);
  float v = nanfix(h[idx]);
  float r = g[c]*(v - m)*inv + b[c];
  stv(&out[idx], fmaxf(r, 0.f));
}

static inline int cdiv(int a, int b){ return (a + b - 1)/b; }

extern "C" void kernel_launch(void* const* d_in, const int* in_sizes, int n_in,
                              void* d_out, int out_size, void* d_ws, size_t ws_size,
                              hipStream_t stream){
  const int IN = 128, HID = 256, T = 4, F1 = 64, F2 = 32;
  const int N = in_sizes[0]/IN;
  const int E = in_sizes[1]/2;
  const int NC1 = T*F1;        // 256
  const int NC2 = T*F2;        // 128

  const float* x      = (const float*)d_in[0];
  const int*   ei     = (const int*)  d_in[1];
  const int*   srcE   = ei;
  const int*   tgtE   = ei + E;
  const float* avgp   = (const float*)d_in[2];
  const float* pre1W  = (const float*)d_in[3];
  const float* pre1b  = (const float*)d_in[4];
  const float* post1W = (const float*)d_in[5];
  const float* post1b = (const float*)d_in[6];
  const float* lin1W  = (const float*)d_in[7];
  const float* lin1b  = (const float*)d_in[8];
  const float* bn1g   = (const float*)d_in[9];
  const float* bn1b   = (const float*)d_in[10];
  const float* pre2W  = (const float*)d_in[11];
  const float* pre2b  = (const float*)d_in[12];
  const float* post2W = (const float*)d_in[13];
  const float* post2b = (const float*)d_in[14];
  const float* lin2W  = (const float*)d_in[15];
  const float* lin2b  = (const float*)d_in[16];
  const float* bn2g   = (const float*)d_in[17];
  const float* bn2b   = (const float*)d_in[18];

  // ---- workspace carve ----
  char* w = (char*)d_ws;
  auto alloc = [&](size_t bytes)->void*{
    void* p = (void*)w; w += (bytes + 255) & ~(size_t)255; return p;
  };
  bf16* WpqT1  = (bf16*)alloc((size_t)2*NC1*IN*2);    float* bpq1   = (float*)alloc(2*NC1*4);
  bf16* WxT1   = (bf16*)alloc((size_t)NC1*IN*2);
  bf16* WaggT1 = (bf16*)alloc((size_t)NC1*12*F1*2);   float* bpost1 = (float*)alloc(NC1*4);
  bf16* lin1WT = (bf16*)alloc((size_t)HID*NC1*2);
  bf16* WpqT2  = (bf16*)alloc((size_t)2*NC2*HID*2);   float* bpq2   = (float*)alloc(2*NC2*4);
  bf16* WxT2   = (bf16*)alloc((size_t)NC2*HID*2);
  bf16* WaggT2 = (bf16*)alloc((size_t)NC2*12*F2*2);   float* bpost2 = (float*)alloc(NC2*4);
  bf16* lin2WT = (bf16*)alloc((size_t)128*NC2*2);
  int* deg_i   = (int*)alloc((size_t)N*4);
  int* offs    = (int*)alloc((size_t)(N+1)*4);
  int* cnt     = (int*)alloc((size_t)N*4);
  int* ssrc    = (int*)alloc((size_t)E*4);
  bf16* x_bf   = (bf16*)alloc((size_t)N*IN*2);
  bf16* PQ     = (bf16*)alloc((size_t)N*512*2);
  bf16* agg12  = (bf16*)alloc((size_t)N*12*NC1*2);   // L2 reuses prefix [N, 12*NC2]
  float* postb = (float*)alloc((size_t)N*256*4);
  bf16* postbb = (bf16*)alloc((size_t)N*256*2);
  float* hpre  = (float*)alloc((size_t)N*256*4);
  bf16* h1b    = (bf16*)alloc((size_t)N*256*2);
  float* stats = (float*)alloc(1024*4);

  // ---- zero accumulators ----
  hipMemsetAsync(deg_i, 0, (size_t)N*4, stream);
  hipMemsetAsync(cnt,   0, (size_t)N*4, stream);
  hipMemsetAsync(stats, 0, 1024*4, stream);

  // ---- repack weights + convert x ----
  k_f2b<<<cdiv(N*IN,256),256,0,stream>>>(x, x_bf, N*IN);
  k_repack_pqT<<<cdiv(2*NC1*IN,256),256,0,stream>>>(pre1W, pre1b, WpqT1, bpq1, IN, F1, T);
  k_repack_postT<<<cdiv(NC1*IN + NC1*12*F1,256),256,0,stream>>>(post1W, post1b, WxT1, WaggT1, bpost1, IN, F1, T);
  k_repack_linT<<<cdiv(HID*NC1,256),256,0,stream>>>(lin1W, lin1WT, NC1, HID);
  k_repack_pqT<<<cdiv(2*NC2*HID,256),256,0,stream>>>(pre2W, pre2b, WpqT2, bpq2, HID, F2, T);
  k_repack_postT<<<cdiv(NC2*HID + NC2*12*F2,256),256,0,stream>>>(post2W, post2b, WxT2, WaggT2, bpost2, HID, F2, T);
  k_repack_linT<<<cdiv(128*NC2,256),256,0,stream>>>(lin2W, lin2WT, NC2, 128);

  // ---- counting sort of edges by target ----
  k_deg<<<cdiv(E,256),256,0,stream>>>(tgtE, deg_i, E);
  k_scan<<<1,1024,0,stream>>>(deg_i, offs, N);
  k_scatter<<<cdiv(E,256),256,0,stream>>>(srcE, tgtE, offs, cnt, ssrc, E);

  int NB = cdiv(N,64);

  // ================= Layer 1 =================
  k_mgemm<bf16><<<dim3(8,NB,1),256,0,stream>>>(x_bf, IN, 0, WpqT1, 0, bpq1, nullptr,
                                               PQ, 512, N, IN, 512, 0);
  k_agg12<NC1,F1><<<N,NC1,0,stream>>>(PQ, ssrc, offs, avgp, agg12, N);
  k_mgemm<float><<<dim3(4,NB,1),256,0,stream>>>(x_bf, IN, 0, WxT1, 0, bpost1, nullptr,
                                                postb, NC1, N, IN, NC1, 0);
  k_mgemm<bf16><<<dim3(1,NB,T),256,0,stream>>>(agg12, 12*NC1, 12*F1, WaggT1, F1*12*F1, nullptr, postb,
                                               postbb, NC1, N, 12*F1, F1, F1);
  k_mgemm<float><<<dim3(4,NB,1),256,0,stream>>>(postbb, NC1, 0, lin1WT, 0, lin1b, nullptr,
                                                hpre, HID, N, NC1, HID, 0);
  k_bn_stats<256><<<cdiv(N,256),256,0,stream>>>(hpre, stats, N);
  k_bn_apply<bf16,256><<<cdiv(N*256,256),256,0,stream>>>(hpre, stats, bn1g, bn1b, h1b, N);

  // ================= Layer 2 =================
  k_mgemm<bf16><<<dim3(4,NB,1),256,0,stream>>>(h1b, HID, 0, WpqT2, 0, bpq2, nullptr,
                                               PQ, 256, N, HID, 256, 0);
  k_agg12<NC2,F2><<<N,NC2,0,stream>>>(PQ, ssrc, offs, avgp, agg12, N);
  k_mgemm<float><<<dim3(2,NB,1),256,0,stream>>>(h1b, HID, 0, WxT2, 0, bpost2, nullptr,
                                                postb, NC2, N, HID, NC2, 0);
  k_mgemm<bf16><<<dim3(1,NB,T),256,0,stream>>>(agg12, 12*NC2, 12*F2, WaggT2, F2*12*F2, nullptr, postb,
                                               postbb, NC2, N, 12*F2, F2, F2);
  k_mgemm<float><<<dim3(2,NB,1),256,0,stream>>>(postbb, NC2, 0, lin2WT, 0, lin2b, nullptr,
                                                hpre, 128, N, NC2, 128, 0);
  k_bn_stats<128><<<cdiv(N,256),128,0,stream>>>(hpre, stats + 512, N);
  k_bn_apply<float,128><<<cdiv(N*128,256),256,0,stream>>>(hpre, stats + 512, bn2g, bn2b, (float*)d_out, N);
}

// Round 5
// 600.762 us; speedup vs baseline: 2.1001x; 1.1302x over previous
//
#include <hip/hip_runtime.h>
#include <hip/hip_bf16.h>
#include <float.h>
#include <math.h>

typedef __hip_bfloat16 bf16;
typedef __attribute__((ext_vector_type(8))) short short8;
typedef __attribute__((ext_vector_type(4))) float f32x4;

__device__ __forceinline__ float bf2f(bf16 v){ return __bfloat162float(v); }
__device__ __forceinline__ void stv(float* p, float v){ *p = v; }
__device__ __forceinline__ void stv(bf16* p, float v){ *p = __float2bfloat16(v); }
__device__ __forceinline__ float nanfix(float v){
  if (v != v) return 0.f;
  return fminf(fmaxf(v, -FLT_MAX), FLT_MAX);
}
__device__ __forceinline__ unsigned short f2bu(float f){
  unsigned u = __float_as_uint(f);
  unsigned r = u + 0x7FFFu + ((u>>16)&1u);
  return (unsigned short)(r>>16);
}
template<int VEC>
__device__ __forceinline__ void ldbf(const bf16* p, float (&o)[VEC]){
  if constexpr (VEC==4){
    ushort4 r = *(const ushort4*)p;
    o[0]=__uint_as_float((unsigned)r.x<<16); o[1]=__uint_as_float((unsigned)r.y<<16);
    o[2]=__uint_as_float((unsigned)r.z<<16); o[3]=__uint_as_float((unsigned)r.w<<16);
  } else {
    ushort2 r = *(const ushort2*)p;
    o[0]=__uint_as_float((unsigned)r.x<<16); o[1]=__uint_as_float((unsigned)r.y<<16);
  }
}

// ---------------- sorting / misc ----------------
__global__ void k_deg(const int* __restrict__ tgt, int* __restrict__ deg, int E){
  int e = blockIdx.x*blockDim.x + threadIdx.x;
  if (e < E) atomicAdd(&deg[tgt[e]], 1);
}

__global__ void k_scan(const int* __restrict__ deg, int* __restrict__ offs, int N){
  __shared__ int sm[1024];
  __shared__ int carry_s;
  int tid = threadIdx.x;
  if (tid == 0){ offs[0] = 0; carry_s = 0; }
  __syncthreads();
  for (int base = 0; base < N; base += 1024){
    int i = base + tid;
    int v = (i < N) ? deg[i] : 0;
    sm[tid] = v; __syncthreads();
    for (int off = 1; off < 1024; off <<= 1){
      int t = (tid >= off) ? sm[tid-off] : 0;
      __syncthreads();
      sm[tid] += t;
      __syncthreads();
    }
    int carry = carry_s;
    if (i < N) offs[i+1] = carry + sm[tid];
    __syncthreads();
    if (tid == 0) carry_s += sm[1023];
    __syncthreads();
  }
}

__global__ void k_scatter(const int* __restrict__ src, const int* __restrict__ tgt,
                          const int* __restrict__ offs, int* __restrict__ cnt,
                          int* __restrict__ ssrc, int E){
  int e = blockIdx.x*blockDim.x + threadIdx.x;
  if (e < E){
    int t = tgt[e];
    int pos = offs[t] + atomicAdd(&cnt[t], 1);
    ssrc[pos] = src[e];
  }
}

__global__ void k_f2b(const float* __restrict__ in, bf16* __restrict__ out, int n){
  int i = blockIdx.x*blockDim.x + threadIdx.x;
  if (i < n) out[i] = __float2bfloat16(in[i]);
}

// ---------------- weight repacks: all produce bf16 B^T [rows][K] ----------------
// WpqT[j][c], j = half*NC + t*F + f  <- preW[t, half*K + c, f]; bpq fp32
__global__ void k_repack_pqT(const float* __restrict__ preW, const float* __restrict__ preB,
                             bf16* __restrict__ WpqT, float* __restrict__ bpq,
                             int K, int F, int T){
  int NC = T*F;
  int total = 2*NC*K;
  int idx = blockIdx.x*blockDim.x + threadIdx.x;
  if (idx < total){
    int j = idx/K, c = idx%K;
    int half = j/NC, jj = j%NC, t = jj/F, f = jj%F;
    WpqT[idx] = __float2bfloat16(preW[(t*2*K + half*K + c)*F + f]);
  }
  if (idx < 2*NC) bpq[idx] = (idx < NC) ? preB[idx] : 0.f;
}

// WxT[j][c] <- postW[t*KP + c, f]; bpost fp32
__global__ void k_repack_xT(const float* __restrict__ postW, const float* __restrict__ postB,
                            bf16* __restrict__ WxT, float* __restrict__ bpost,
                            int KX, int F, int T){
  int NC = T*F; int KP = KX + 12*F;
  int totalx = NC*KX;
  int idx = blockIdx.x*blockDim.x + threadIdx.x;
  if (idx < totalx){
    int j = idx/KX, c = idx%KX, t = j/F, f = j%F;
    WxT[idx] = __float2bfloat16(postW[(t*KP + c)*F + f]);
  }
  if (idx < NC) bpost[idx] = postB[idx];
}

// Wagg3[t][s*F + f][k] <- postW[t, KX + s*4F + k, f]   (k in [0,4F))
__global__ void k_repack_agg3(const float* __restrict__ postW, bf16* __restrict__ Wagg3,
                              int KX, int F, int T){
  int K4F = 4*F; int KP = KX + 12*F;
  int total = T*3*F*K4F;
  int idx = blockIdx.x*blockDim.x + threadIdx.x;
  if (idx < total){
    int k = idx % K4F; int r = idx / K4F;
    int zr = r % (3*F); int t = r / (3*F);
    int s = zr / F, f = zr % F;
    Wagg3[idx] = __float2bfloat16(postW[((size_t)(t*KP + KX + s*K4F + k))*F + f]);
  }
}

// WlinT[j][c] <- linW[c*NC + j]
__global__ void k_repack_linT(const float* __restrict__ linW, bf16* __restrict__ WlinT,
                              int K, int NC){
  int idx = blockIdx.x*blockDim.x + threadIdx.x;
  if (idx < NC*K){
    int j = idx/K, c = idx%K;
    WlinT[idx] = __float2bfloat16(linW[c*NC + j]);
  }
}

// ---------------- MFMA GEMM: C[N, *] = A[N,K](bf16) @ Bt[NC,K]^T (bf16) ----------------
template<typename TO>
__global__ __launch_bounds__(256) void k_mgemm(
    const bf16* __restrict__ A, int lda, int AzStride,
    const bf16* __restrict__ Bt, int BzStride,
    const float* __restrict__ bias,
    const float* __restrict__ Cin, TO* __restrict__ Cout, int ldc,
    int N, int K, int NCz, int czStride)
{
  __shared__ __align__(16) bf16 As[64*40];
  __shared__ __align__(16) bf16 Bs[64*40];
  int z = blockIdx.z;
  const bf16* Az = A + (size_t)z*AzStride;
  const bf16* Bz = Bt + (size_t)z*BzStride;
  int n0 = blockIdx.y*64;
  int j0 = blockIdx.x*64;
  int tid = threadIdx.x;
  int srow = tid>>2, skoff = (tid&3)*8;
  int wave = tid>>6, lane = tid&63;
  int wy = (wave>>1)*32, wx = (wave&1)*32;
  int l15 = lane&15, q = lane>>4;
  f32x4 acc[2][2] = {};
  for (int k0 = 0; k0 < K; k0 += 32){
    uint4 av = {0,0,0,0};
    int ar = n0 + srow;
    if (ar < N) av = *(const uint4*)(Az + (size_t)ar*lda + k0 + skoff);
    *(uint4*)&As[srow*40 + skoff] = av;
    uint4 bv = {0,0,0,0};
    int br = j0 + srow;
    if (br < NCz) bv = *(const uint4*)(Bz + (size_t)br*K + k0 + skoff);
    *(uint4*)&Bs[srow*40 + skoff] = bv;
    __syncthreads();
    short8 af[2], bfr[2];
    #pragma unroll
    for (int i = 0; i < 2; i++){
      af[i]  = *(const short8*)&As[(wy + i*16 + l15)*40 + q*8];
      bfr[i] = *(const short8*)&Bs[(wx + i*16 + l15)*40 + q*8];
    }
    #pragma unroll
    for (int mi = 0; mi < 2; mi++)
      #pragma unroll
      for (int ni = 0; ni < 2; ni++)
        acc[mi][ni] = __builtin_amdgcn_mfma_f32_16x16x32_bf16(af[mi], bfr[ni], acc[mi][ni], 0, 0, 0);
    __syncthreads();
  }
  #pragma unroll
  for (int mi = 0; mi < 2; mi++){
    #pragma unroll
    for (int ni = 0; ni < 2; ni++){
      #pragma unroll
      for (int r = 0; r < 4; r++){
        int n  = n0 + wy + mi*16 + q*4 + r;
        int jj = j0 + wx + ni*16 + l15;
        if (n < N && jj < NCz){
          int jg = z*czStride + jj;
          float v = acc[mi][ni][r];
          if (bias) v += bias[jg];
          if (Cin)  v += Cin[(size_t)n*ldc + jg];
          stv(&Cout[(size_t)n*ldc + jg], v);
        }
      }
    }
  }
}

// ---------------- MFMA post-agg GEMM with scaler combine ----------------
// Per z (tower): C[n, z*COLS + jj] = Cin + C0 + s1[n]*C1 + s2[n]*C2,
// Cs[n,jj] = sum_k agg[n, z*4F + k] * Wagg3[z][s*COLS + jj][k], K4F = 4*COLS.
template<int COLS, int K4F>
__global__ __launch_bounds__(256) void k_postagg(
    const bf16* __restrict__ agg, int lda,
    const bf16* __restrict__ Wagg3,
    const float* __restrict__ Cin, const float* __restrict__ scal,
    bf16* __restrict__ Cout, int ldc, int N)
{
  constexpr int ROWS3 = 3*COLS;
  constexpr int NI = COLS/32;   // 2 for COLS=64, 1 for COLS=32
  __shared__ __align__(16) bf16 As[64*40];
  __shared__ __align__(16) bf16 Bs[ROWS3*40];
  int z = blockIdx.z;
  const bf16* Az = agg + (size_t)z*K4F;
  const bf16* Bz = Wagg3 + (size_t)z*ROWS3*K4F;
  int n0 = blockIdx.y*64;
  int tid = threadIdx.x;
  int srow = tid>>2, skoff = (tid&3)*8;
  int wave = tid>>6, lane = tid&63;
  int wy = (wave>>1)*32;
  int wx = (wave&1)*(COLS/2);
  int l15 = lane&15, q = lane>>4;
  f32x4 acc[2][NI][3] = {};
  for (int k0 = 0; k0 < K4F; k0 += 32){
    uint4 av = {0,0,0,0};
    int ar = n0 + srow;
    if (ar < N) av = *(const uint4*)(Az + (size_t)ar*lda + k0 + skoff);
    *(uint4*)&As[srow*40 + skoff] = av;
    for (int r = srow; r < ROWS3; r += 64){
      uint4 bv = *(const uint4*)(Bz + (size_t)r*K4F + k0 + skoff);
      *(uint4*)&Bs[r*40 + skoff] = bv;
    }
    __syncthreads();
    short8 af[2];
    #pragma unroll
    for (int i = 0; i < 2; i++)
      af[i] = *(const short8*)&As[(wy + i*16 + l15)*40 + q*8];
    #pragma unroll
    for (int s = 0; s < 3; s++){
      #pragma unroll
      for (int ni = 0; ni < NI; ni++){
        short8 bfr = *(const short8*)&Bs[(s*COLS + wx + ni*16 + l15)*40 + q*8];
        #pragma unroll
        for (int mi = 0; mi < 2; mi++)
          acc[mi][ni][s] = __builtin_amdgcn_mfma_f32_16x16x32_bf16(af[mi], bfr, acc[mi][ni][s], 0, 0, 0);
      }
    }
    __syncthreads();
  }
  #pragma unroll
  for (int mi = 0; mi < 2; mi++){
    #pragma unroll
    for (int ni = 0; ni < NI; ni++){
      int jj = wx + ni*16 + l15;
      int jg = z*COLS + jj;
      #pragma unroll
      for (int r = 0; r < 4; r++){
        int n = n0 + wy + mi*16 + q*4 + r;
        if (n < N){
          float s1 = scal[2*n], s2 = scal[2*n+1];
          float v = Cin[(size_t)n*ldc + jg]
                  + acc[mi][ni][0][r] + s1*acc[mi][ni][1][r] + s2*acc[mi][ni][2][r];
          Cout[(size_t)n*ldc + jg] = __float2bfloat16(v);
        }
      }
    }
  }
}

// ---------------- per-node PNA aggregation -> agg [N, T*4F] bf16 + scal ----------------
// node per wave, 4 nodes per block; VEC = NC/64 cols per lane.
template<int NC, int F>
__global__ __launch_bounds__(256) void k_agg(const bf16* __restrict__ PQ,
    const int* __restrict__ ssrc, const int* __restrict__ offs,
    const float* __restrict__ avgp,
    bf16* __restrict__ agg, float* __restrict__ scal, int N){
  constexpr int VEC = NC/64;
  int wave = threadIdx.x>>6, lane = threadIdx.x&63;
  int n = blockIdx.x*4 + wave;
  if (n >= N) return;
  int c0 = lane*VEC;
  float p[VEC];
  ldbf<VEC>(PQ + (size_t)n*2*NC + c0, p);
  int s0 = offs[n], s1 = offs[n+1];
  float sum[VEC], sq[VEC], mn[VEC], mx[VEC];
  #pragma unroll
  for (int v=0;v<VEC;v++){ sum[v]=0.f; sq[v]=0.f; mn[v]=FLT_MAX; mx[v]=-FLT_MAX; }
  const bf16* Q = PQ + NC + c0;
  int i = s0;
  for (; i+1 < s1; i += 2){
    int sa = ssrc[i], sb = ssrc[i+1];
    float qa[VEC], qb[VEC];
    ldbf<VEC>(Q + (size_t)sa*2*NC, qa);
    ldbf<VEC>(Q + (size_t)sb*2*NC, qb);
    #pragma unroll
    for (int v=0;v<VEC;v++){
      float ma = p[v]+qa[v], mb = p[v]+qb[v];
      sum[v] += ma+mb; sq[v] += ma*ma+mb*mb;
      mn[v] = fminf(mn[v], fminf(ma,mb));
      mx[v] = fmaxf(mx[v], fmaxf(ma,mb));
    }
  }
  if (i < s1){
    int sa = ssrc[i];
    float qa[VEC];
    ldbf<VEC>(Q + (size_t)sa*2*NC, qa);
    #pragma unroll
    for (int v=0;v<VEC;v++){
      float ma = p[v]+qa[v];
      sum[v]+=ma; sq[v]+=ma*ma; mn[v]=fminf(mn[v],ma); mx[v]=fmaxf(mx[v],ma);
    }
  }
  int deg = s1-s0;
  float degc = fmaxf((float)deg, 1.f);
  unsigned short um[VEC], un[VEC], ux[VEC], us[VEC];
  #pragma unroll
  for (int v=0;v<VEC;v++){
    float mean = sum[v]/degc;
    float var = fmaxf(sq[v]/degc - mean*mean, 0.f);
    float sd = sqrtf(var + 1e-5f);
    float mnv = deg>0 ? mn[v] : 0.f;
    float mxv = deg>0 ? mx[v] : 0.f;
    um[v]=f2bu(mean); un[v]=f2bu(mnv); ux[v]=f2bu(mxv); us[v]=f2bu(sd);
  }
  int t = c0 / F, f0 = c0 % F;
  bf16* base = agg + (size_t)n*4*NC + (size_t)t*4*F + f0;
  if constexpr (VEC==4){
    *(ushort4*)(base)       = make_ushort4(um[0],um[1],um[2],um[3]);
    *(ushort4*)(base + F)   = make_ushort4(un[0],un[1],un[2],un[3]);
    *(ushort4*)(base + 2*F) = make_ushort4(ux[0],ux[1],ux[2],ux[3]);
    *(ushort4*)(base + 3*F) = make_ushort4(us[0],us[1],us[2],us[3]);
  } else {
    *(ushort2*)(base)       = make_ushort2(um[0],um[1]);
    *(ushort2*)(base + F)   = make_ushort2(un[0],un[1]);
    *(ushort2*)(base + 2*F) = make_ushort2(ux[0],ux[1]);
    *(ushort2*)(base + 3*F) = make_ushort2(us[0],us[1]);
  }
  if (lane==0){
    float dlog = logf(degc + 1.f);
    float avg = *avgp;
    scal[2*n]   = dlog/avg;
    scal[2*n+1] = avg/dlog;
  }
}

// ---------------- batch norm ----------------
template<int C>
__global__ void k_bn_stats(const float* __restrict__ h, float* __restrict__ stats, int N){
  int c = threadIdx.x;
  int n0 = blockIdx.x*256;
  int n1 = min(n0 + 256, N);
  float s = 0.f, q = 0.f;
  for (int n = n0; n < n1; n++){
    float v = nanfix(h[(size_t)n*C + c]);
    s += v; q += v*v;
  }
  atomicAdd(&stats[c], s);
  atomicAdd(&stats[C + c], q);
}

template<typename TO, int C>
__global__ void k_bn_apply(const float* __restrict__ h, const float* __restrict__ stats,
     const float* __restrict__ g, const float* __restrict__ b,
     TO* __restrict__ out, int N){
  int idx = blockIdx.x*blockDim.x + threadIdx.x;
  if (idx >= N*C) return;
  int c = idx % C;
  float fn = (float)N;
  float m = stats[c]/fn;
  float var = fmaxf(stats[C + c]/fn - m*m, 0.f);
  float inv = rsqrtf(var + 1e-5f);
  float v = nanfix(h[idx]);
  float r = g[c]*(v - m)*inv + b[c];
  stv(&out[idx], fmaxf(r, 0.f));
}

static inline int cdiv(int a, int b){ return (a + b - 1)/b; }

extern "C" void kernel_launch(void* const* d_in, const int* in_sizes, int n_in,
                              void* d_out, int out_size, void* d_ws, size_t ws_size,
                              hipStream_t stream){
  const int IN = 128, HID = 256, T = 4, F1 = 64, F2 = 32;
  const int N = in_sizes[0]/IN;
  const int E = in_sizes[1]/2;
  const int NC1 = T*F1;        // 256
  const int NC2 = T*F2;        // 128

  const float* x      = (const float*)d_in[0];
  const int*   ei     = (const int*)  d_in[1];
  const int*   srcE   = ei;
  const int*   tgtE   = ei + E;
  const float* avgp   = (const float*)d_in[2];
  const float* pre1W  = (const float*)d_in[3];
  const float* pre1b  = (const float*)d_in[4];
  const float* post1W = (const float*)d_in[5];
  const float* post1b = (const float*)d_in[6];
  const float* lin1W  = (const float*)d_in[7];
  const float* lin1b  = (const float*)d_in[8];
  const float* bn1g   = (const float*)d_in[9];
  const float* bn1b   = (const float*)d_in[10];
  const float* pre2W  = (const float*)d_in[11];
  const float* pre2b  = (const float*)d_in[12];
  const float* post2W = (const float*)d_in[13];
  const float* post2b = (const float*)d_in[14];
  const float* lin2W  = (const float*)d_in[15];
  const float* lin2b  = (const float*)d_in[16];
  const float* bn2g   = (const float*)d_in[17];
  const float* bn2b   = (const float*)d_in[18];

  // ---- workspace carve ----
  char* w = (char*)d_ws;
  auto alloc = [&](size_t bytes)->void*{
    void* p = (void*)w; w += (bytes + 255) & ~(size_t)255; return p;
  };
  bf16* WpqT1  = (bf16*)alloc((size_t)2*NC1*IN*2);    float* bpq1   = (float*)alloc(2*NC1*4);
  bf16* WxT1   = (bf16*)alloc((size_t)NC1*IN*2);      float* bpost1 = (float*)alloc(NC1*4);
  bf16* Wagg31 = (bf16*)alloc((size_t)T*3*F1*4*F1*2);
  bf16* lin1WT = (bf16*)alloc((size_t)HID*NC1*2);
  bf16* WpqT2  = (bf16*)alloc((size_t)2*NC2*HID*2);   float* bpq2   = (float*)alloc(2*NC2*4);
  bf16* WxT2   = (bf16*)alloc((size_t)NC2*HID*2);     float* bpost2 = (float*)alloc(NC2*4);
  bf16* Wagg32 = (bf16*)alloc((size_t)T*3*F2*4*F2*2);
  bf16* lin2WT = (bf16*)alloc((size_t)128*NC2*2);
  int* deg_i   = (int*)alloc((size_t)N*4);
  int* offs    = (int*)alloc((size_t)(N+1)*4);
  int* cnt     = (int*)alloc((size_t)N*4);
  int* ssrc    = (int*)alloc((size_t)E*4);
  bf16* x_bf   = (bf16*)alloc((size_t)N*IN*2);
  bf16* PQ     = (bf16*)alloc((size_t)N*512*2);
  bf16* aggb   = (bf16*)alloc((size_t)N*4*NC1*2);    // L2 reuses prefix [N, 4*NC2]
  float* scal  = (float*)alloc((size_t)N*2*4);
  float* postb = (float*)alloc((size_t)N*256*4);
  bf16* postbb = (bf16*)alloc((size_t)N*256*2);
  float* hpre  = (float*)alloc((size_t)N*256*4);
  bf16* h1b    = (bf16*)alloc((size_t)N*256*2);
  float* stats = (float*)alloc(1024*4);

  // ---- zero accumulators ----
  hipMemsetAsync(deg_i, 0, (size_t)N*4, stream);
  hipMemsetAsync(cnt,   0, (size_t)N*4, stream);
  hipMemsetAsync(stats, 0, 1024*4, stream);

  // ---- repack weights + convert x ----
  k_f2b<<<cdiv(N*IN,256),256,0,stream>>>(x, x_bf, N*IN);
  k_repack_pqT<<<cdiv(2*NC1*IN,256),256,0,stream>>>(pre1W, pre1b, WpqT1, bpq1, IN, F1, T);
  k_repack_xT<<<cdiv(NC1*IN,256),256,0,stream>>>(post1W, post1b, WxT1, bpost1, IN, F1, T);
  k_repack_agg3<<<cdiv(T*3*F1*4*F1,256),256,0,stream>>>(post1W, Wagg31, IN, F1, T);
  k_repack_linT<<<cdiv(HID*NC1,256),256,0,stream>>>(lin1W, lin1WT, NC1, HID);
  k_repack_pqT<<<cdiv(2*NC2*HID,256),256,0,stream>>>(pre2W, pre2b, WpqT2, bpq2, HID, F2, T);
  k_repack_xT<<<cdiv(NC2*HID,256),256,0,stream>>>(post2W, post2b, WxT2, bpost2, HID, F2, T);
  k_repack_agg3<<<cdiv(T*3*F2*4*F2,256),256,0,stream>>>(post2W, Wagg32, HID, F2, T);
  k_repack_linT<<<cdiv(128*NC2,256),256,0,stream>>>(lin2W, lin2WT, NC2, 128);

  // ---- counting sort of edges by target ----
  k_deg<<<cdiv(E,256),256,0,stream>>>(tgtE, deg_i, E);
  k_scan<<<1,1024,0,stream>>>(deg_i, offs, N);
  k_scatter<<<cdiv(E,256),256,0,stream>>>(srcE, tgtE, offs, cnt, ssrc, E);

  int NB = cdiv(N,64);

  // ================= Layer 1 =================
  k_mgemm<bf16><<<dim3(8,NB,1),256,0,stream>>>(x_bf, IN, 0, WpqT1, 0, bpq1, nullptr,
                                               PQ, 512, N, IN, 512, 0);
  k_agg<256,64><<<cdiv(N,4),256,0,stream>>>(PQ, ssrc, offs, avgp, aggb, scal, N);
  k_mgemm<float><<<dim3(4,NB,1),256,0,stream>>>(x_bf, IN, 0, WxT1, 0, bpost1, nullptr,
                                                postb, NC1, N, IN, NC1, 0);
  k_postagg<64,256><<<dim3(1,NB,T),256,0,stream>>>(aggb, 4*NC1, Wagg31, postb, scal,
                                                   postbb, NC1, N);
  k_mgemm<float><<<dim3(4,NB,1),256,0,stream>>>(postbb, NC1, 0, lin1WT, 0, lin1b, nullptr,
                                                hpre, HID, N, NC1, HID, 0);
  k_bn_stats<256><<<cdiv(N,256),256,0,stream>>>(hpre, stats, N);
  k_bn_apply<bf16,256><<<cdiv(N*256,256),256,0,stream>>>(hpre, stats, bn1g, bn1b, h1b, N);

  // ================= Layer 2 =================
  k_mgemm<bf16><<<dim3(4,NB,1),256,0,stream>>>(h1b, HID, 0, WpqT2, 0, bpq2, nullptr,
                                               PQ, 256, N, HID, 256, 0);
  k_agg<128,32><<<cdiv(N,4),256,0,stream>>>(PQ, ssrc, offs, avgp, aggb, scal, N);
  k_mgemm<float><<<dim3(2,NB,1),256,0,stream>>>(h1b, HID, 0, WxT2, 0, bpost2, nullptr,
                                                postb, NC2, N, HID, NC2, 0);
  k_postagg<32,128><<<dim3(1,NB,T),256,0,stream>>>(aggb, 4*NC2, Wagg32, postb, scal,
                                                   postbb, NC2, N);
  k_mgemm<float><<<dim3(2,NB,1),256,0,stream>>>(postbb, NC2, 0, lin2WT, 0, lin2b, nullptr,
                                                hpre, 128, N, NC2, 128, 0);
  k_bn_stats<128><<<cdiv(N,256),128,0,stream>>>(hpre, stats + 512, N);
  k_bn_apply<float,128><<<cdiv(N*128,256),256,0,stream>>>(hpre, stats + 512, bn2g, bn2b, (float*)d_out, N);
}